// Round 1
// baseline (228.258 us; speedup 1.0000x reference)
//
#include <hip/hip_runtime.h>

// Element-wise threshold-round with reversed output order.
// y[i] = (x[i]-trunc(x[i]) > thr) ? rint(x[i]) : floor(x[i]);  out = y[::-1]
//
// Memory-bound streaming: 128 MiB in + 128 MiB out, zero reuse.
// Structure:
//  - vec4 (16 B/lane) nontemporal load+store, both lane-ascending contiguous.
//    The reversal is done by swapping components within the vec4 plus a
//    cross-lane shuffle lane l <-> 63-l, so each wave stores one ascending
//    1 KiB segment.
//  - Grid-stride with 2048 blocks (256 thr): 32 waves/CU resident, each
//    thread owns 16 groups. Main loop is manually 4x unrolled so 4
//    independent global_load_dwordx4 are in flight per wave (ILP), instead
//    of one load per block lifetime with 32768 tiny blocks.

typedef float vfloat4 __attribute__((ext_vector_type(4)));

__device__ __forceinline__ float thr_round(float x, float thr) {
    float f = x - truncf(x);
    return (f > thr) ? rintf(x) : floorf(x);
}

// Process input group t: apply op with component reversal, then cross-lane
// reverse so that lane l holds the result whose OUTPUT group ascends with l.
__device__ __forceinline__ vfloat4 process_group(const vfloat4* __restrict__ x4,
                                                 int t, int src, float thr) {
    vfloat4 v = __builtin_nontemporal_load(&x4[t]);
    vfloat4 r;
    r.x = thr_round(v.w, thr);
    r.y = thr_round(v.z, thr);
    r.z = thr_round(v.y, thr);
    r.w = thr_round(v.x, thr);
    vfloat4 s;
    s.x = __shfl(r.x, src);
    s.y = __shfl(r.y, src);
    s.z = __shfl(r.z, src);
    s.w = __shfl(r.w, src);
    return s;
}

__global__ __launch_bounds__(256) void threshold_rev_kernel(
    const vfloat4* __restrict__ x4,
    const float* __restrict__ threshold,
    vfloat4* __restrict__ out4,
    int n4 /* number of float4 groups = N/4; multiple of 64 */) {
    const float thr = threshold[0];
    const int lane = threadIdx.x & 63;
    const int src = 63 - lane;           // shuffle source: lane 63-l
    const int stride = gridDim.x * blockDim.x;
    int t = blockIdx.x * blockDim.x + threadIdx.x;

    // Main loop: 4 groups per iteration, loads issued back-to-back for ILP.
    for (; t + 3 * stride < n4; t += 4 * stride) {
        const int t0 = t;
        const int t1 = t + stride;
        const int t2 = t + 2 * stride;
        const int t3 = t + 3 * stride;
        vfloat4 s0 = process_group(x4, t0, src, thr);
        vfloat4 s1 = process_group(x4, t1, src, thr);
        vfloat4 s2 = process_group(x4, t2, src, thr);
        vfloat4 s3 = process_group(x4, t3, src, thr);
        // input group of lane (63-l) is wave_base+63-l; its output group is
        // n4-1-(wave_base+63-l) = (n4-64-wave_base) + l -> ascending in lane.
        __builtin_nontemporal_store(s0, &out4[(n4 - 64 - (t0 - lane)) + lane]);
        __builtin_nontemporal_store(s1, &out4[(n4 - 64 - (t1 - lane)) + lane]);
        __builtin_nontemporal_store(s2, &out4[(n4 - 64 - (t2 - lane)) + lane]);
        __builtin_nontemporal_store(s3, &out4[(n4 - 64 - (t3 - lane)) + lane]);
    }
    // Remainder (n4 % (4*stride) != 0 case); guard is wave-uniform since
    // n4 and stride are multiples of 64.
    for (; t < n4; t += stride) {
        vfloat4 s = process_group(x4, t, src, thr);
        __builtin_nontemporal_store(s, &out4[(n4 - 64 - (t - lane)) + lane]);
    }
}

extern "C" void kernel_launch(void* const* d_in, const int* in_sizes, int n_in,
                              void* d_out, int out_size, void* d_ws, size_t ws_size,
                              hipStream_t stream) {
    const vfloat4* x4 = (const vfloat4*)d_in[0];
    const float* thr = (const float*)d_in[1];
    vfloat4* out4 = (vfloat4*)d_out;
    int n = in_sizes[0];       // 33554432
    int n4 = n / 4;            // 8388608 groups
    int block = 256;
    int max_blocks = 2048;     // 8 blocks/CU on 256 CUs; grid-stride the rest
    int grid = (n4 + block - 1) / block;
    if (grid > max_blocks) grid = max_blocks;
    threshold_rev_kernel<<<grid, block, 0, stream>>>(x4, thr, out4, n4);
}

// Round 2
// 219.788 us; speedup vs baseline: 1.0385x; 1.0385x over previous
//
#include <hip/hip_runtime.h>

// Element-wise threshold-round with reversed output order.
// y[i] = (x[i]-trunc(x[i]) > thr) ? rint(x[i]) : floor(x[i]);  out = y[::-1]
//
// Memory-bound streaming: 128 MiB in + 128 MiB out, zero reuse.
// Structure (post R1 post-mortem):
//  - DENSE block->address mapping (R1 showed grid-stride with 2048 blocks
//    scatters ~16k active 1KiB segments across 512 MiB and loses DRAM page
//    locality: kernel 59->68us). Block b owns 1024 consecutive groups.
//  - 4 groups/thread at +256-group offsets: 4 independent
//    global_load_dwordx4 in flight per wave before any dependent shuffle,
//    and 4x fewer block launches than the one-shot version (8192 vs 32768).
//  - vec4 load+store both lane-ascending contiguous: reversal done by
//    component swap within the vec4 + cross-lane shuffle l <-> 63-l, so
//    each wave stores ascending 1 KiB segments.
//  - Nontemporal hints: pure streaming, zero reuse.

typedef float vfloat4 __attribute__((ext_vector_type(4)));

constexpr int BLOCK = 256;
constexpr int GPT = 4;             // groups per thread
constexpr int GPB = BLOCK * GPT;   // 1024 groups per block (16 KiB in/out)

__device__ __forceinline__ float thr_round(float x, float thr) {
    float f = x - truncf(x);
    return (f > thr) ? rintf(x) : floorf(x);
}

// Apply op with component reversal, then cross-lane reverse so lane l holds
// the result whose OUTPUT group ascends with l.
__device__ __forceinline__ vfloat4 rev_op(vfloat4 v, int src, float thr) {
    vfloat4 r;
    r.x = thr_round(v.w, thr);
    r.y = thr_round(v.z, thr);
    r.z = thr_round(v.y, thr);
    r.w = thr_round(v.x, thr);
    vfloat4 s;
    s.x = __shfl(r.x, src);
    s.y = __shfl(r.y, src);
    s.z = __shfl(r.z, src);
    s.w = __shfl(r.w, src);
    return s;
}

__global__ __launch_bounds__(BLOCK) void threshold_rev_kernel(
    const vfloat4* __restrict__ x4,
    const float* __restrict__ threshold,
    vfloat4* __restrict__ out4,
    int n4 /* number of float4 groups = N/4; multiple of 64 */) {
    const float thr = threshold[0];
    const int tid = threadIdx.x;
    const int lane = tid & 63;
    const int src = 63 - lane;          // shuffle source: lane 63-l
    const int gb = blockIdx.x * GPB;    // first group owned by this block

    if (gb + GPB <= n4) {
        // Fast path: whole chunk in bounds. Issue all 4 loads back-to-back.
        const int t0 = gb + tid;
        const int t1 = t0 + BLOCK;
        const int t2 = t0 + 2 * BLOCK;
        const int t3 = t0 + 3 * BLOCK;
        vfloat4 v0 = __builtin_nontemporal_load(&x4[t0]);
        vfloat4 v1 = __builtin_nontemporal_load(&x4[t1]);
        vfloat4 v2 = __builtin_nontemporal_load(&x4[t2]);
        vfloat4 v3 = __builtin_nontemporal_load(&x4[t3]);

        vfloat4 s0 = rev_op(v0, src, thr);
        vfloat4 s1 = rev_op(v1, src, thr);
        vfloat4 s2 = rev_op(v2, src, thr);
        vfloat4 s3 = rev_op(v3, src, thr);

        // input group of lane (63-l) is wave_base+63-l; its output group is
        // n4-1-(wave_base+63-l) = (n4-64-wave_base) + l -> ascending in lane.
        __builtin_nontemporal_store(s0, &out4[(n4 - 64 - (t0 - lane)) + lane]);
        __builtin_nontemporal_store(s1, &out4[(n4 - 64 - (t1 - lane)) + lane]);
        __builtin_nontemporal_store(s2, &out4[(n4 - 64 - (t2 - lane)) + lane]);
        __builtin_nontemporal_store(s3, &out4[(n4 - 64 - (t3 - lane)) + lane]);
    } else {
        // Tail: per-group guard. n4 is a multiple of 64 so the guard is
        // wave-uniform (whole wave in or out) and the shuffle stays valid.
        for (int k = 0; k < GPT; ++k) {
            const int t = gb + tid + k * BLOCK;
            if (t < n4) {
                vfloat4 v = __builtin_nontemporal_load(&x4[t]);
                vfloat4 s = rev_op(v, src, thr);
                __builtin_nontemporal_store(s, &out4[(n4 - 64 - (t - lane)) + lane]);
            }
        }
    }
}

extern "C" void kernel_launch(void* const* d_in, const int* in_sizes, int n_in,
                              void* d_out, int out_size, void* d_ws, size_t ws_size,
                              hipStream_t stream) {
    const vfloat4* x4 = (const vfloat4*)d_in[0];
    const float* thr = (const float*)d_in[1];
    vfloat4* out4 = (vfloat4*)d_out;
    int n = in_sizes[0];       // 33554432
    int n4 = n / 4;            // 8388608 groups
    int grid = (n4 + GPB - 1) / GPB;   // 8192 blocks, dense mapping
    threshold_rev_kernel<<<grid, BLOCK, 0, stream>>>(x4, thr, out4, n4);
}